// Round 8
// baseline (20.685 us; speedup 1.0000x reference)
//
#include <hip/hip_runtime.h>
#include <hip/hip_bf16.h>

// B=64, C=512, Q=64, D=512, fp32 in/out.
// out[b,c,q] = sum_d H[b,c,d]*U'[b,q,d] + s_u[b,q]
//   U'[q,d] = w_hu[d]*U[q,d] + w_h[d]   (folds s_h into the GEMM)
//   s_u[q]  = sum_d w_u[d]*U[q,d]
// 256 blocks (1/CU) x 512 threads. R7 structure (split staging, scalar w
// loads, one small + one main barrier) with the H prefetch ring deepened
// 4 -> 8 (lead 7): 14 loads in flight per wave = 112 KB/CU outstanding,
// so the K-loop stays BW-paced even at ~2-4x nominal HBM latency.

#define Bn 64
#define Cn 512
#define Qn 64
#define Dn 512

typedef __bf16 bf16x8 __attribute__((ext_vector_type(8)));
typedef float  f32x4  __attribute__((ext_vector_type(4)));

__global__ __launch_bounds__(512, 1)
void sim_kernel(const float* __restrict__ H, const float* __restrict__ U,
                const float* __restrict__ w, float* __restrict__ out)
{
    // Us[kt][hh][p][j]: element d = kt*32 + hh*8 + j of q with (q^(kt&7))==p
    __shared__ __bf16 Us[16][4][64][8];   // 64 KB
    __shared__ float  su_p[8][64];        // per-wave s_u partials (2 KB)

    // XCD-contiguous mapping: XCD x (= bid&7) owns batches 8x..8x+7.
    const int r  = (int)blockIdx.x;       // 0..255
    const int x  = r & 7;
    const int i  = r >> 3;                // 0..31
    const int b  = x * 8 + (i >> 2);
    const int c0 = (i & 3) * 128;

    const int t    = (int)threadIdx.x;
    const int wv   = t >> 6;              // wave 0..7: rows c0+wv*16..+15
    const int lane = t & 63;
    const int ql   = lane & 15;
    const int hh   = lane >> 4;

    // ---- H ring prologue: 7 pairs issued FIRST (oldest in VMEM FIFO) ----
    const float* __restrict__ hp =
        H + ((size_t)(b * Cn + c0 + wv * 16 + ql)) * Dn + hh * 8;
    f32x4 ha[8], hb[8];
#pragma unroll
    for (int p = 0; p < 7; ++p) {
        ha[p] = *(const f32x4*)(hp + 32 * p);
        hb[p] = *(const f32x4*)(hp + 32 * p + 4);
    }

    // ---- staging: slot s (0..4095) = (kt, hv, q=lane); thread t owns
    // slots t + 512*j, j=0..7. (kt,hv) wave-uniform -> scalar w loads. ----
    const float* __restrict__ Ubase = U + ((size_t)(b * Qn + lane)) * Dn;
    float su_acc = 0.f;

    auto stage_slot = [&](int j) {
        const int slot = t + 512 * j;
        const int kt = __builtin_amdgcn_readfirstlane(slot >> 8);
        const int hv = __builtin_amdgcn_readfirstlane((slot >> 6) & 3);
        const int d0 = kt * 32 + hv * 8;
        f32x4 u0  = *(const f32x4*)(Ubase + d0);
        f32x4 u1  = *(const f32x4*)(Ubase + d0 + 4);
        f32x4 wh0 = *(const f32x4*)(w + d0);
        f32x4 wh1 = *(const f32x4*)(w + d0 + 4);
        f32x4 wu0 = *(const f32x4*)(w + 512 + d0);
        f32x4 wu1 = *(const f32x4*)(w + 512 + d0 + 4);
        f32x4 wm0 = *(const f32x4*)(w + 1024 + d0);
        f32x4 wm1 = *(const f32x4*)(w + 1024 + d0 + 4);
        bf16x8 v;
#pragma unroll
        for (int e = 0; e < 4; ++e) {
            su_acc += wu0[e] * u0[e] + wu1[e] * u1[e];
            v[e]     = (__bf16)__builtin_fmaf(wm0[e], u0[e], wh0[e]);
            v[e + 4] = (__bf16)__builtin_fmaf(wm1[e], u1[e], wh1[e]);
        }
        *(bf16x8*)&Us[kt][hv][lane ^ (kt & 7)][0] = v;
    };

    // ---- compute step ----
    f32x4 acc[4] = {{0.f,0.f,0.f,0.f},{0.f,0.f,0.f,0.f},
                    {0.f,0.f,0.f,0.f},{0.f,0.f,0.f,0.f}};

    auto compute_step = [&](int k) {
        f32x4 ca = ha[k & 7], cb = hb[k & 7];
        if (k + 7 < 16) {
            ha[(k + 7) & 7] = *(const f32x4*)(hp + 32 * (k + 7));
            hb[(k + 7) & 7] = *(const f32x4*)(hp + 32 * (k + 7) + 4);
        }
        bf16x8 a;
#pragma unroll
        for (int e = 0; e < 4; ++e) {
            a[e]     = (__bf16)ca[e];
            a[e + 4] = (__bf16)cb[e];
        }
        const int pq = ql ^ (k & 7);
        bf16x8 f0 = *(const bf16x8*)&Us[k][hh][pq +  0][0];
        bf16x8 f1 = *(const bf16x8*)&Us[k][hh][pq + 16][0];
        bf16x8 f2 = *(const bf16x8*)&Us[k][hh][pq + 32][0];
        bf16x8 f3 = *(const bf16x8*)&Us[k][hh][pq + 48][0];
        acc[0] = __builtin_amdgcn_mfma_f32_16x16x32_bf16(a, f0, acc[0], 0, 0, 0);
        acc[1] = __builtin_amdgcn_mfma_f32_16x16x32_bf16(a, f1, acc[1], 0, 0, 0);
        acc[2] = __builtin_amdgcn_mfma_f32_16x16x32_bf16(a, f2, acc[2], 0, 0, 0);
        acc[3] = __builtin_amdgcn_mfma_f32_16x16x32_bf16(a, f3, acc[3], 0, 0, 0);
    };

    // ---- Phase A: stage K-tiles 0..3 only (1/4 of staging) ----
    stage_slot(0);
    stage_slot(1);
    __syncthreads();                      // barrier 1 (small drain)

    // ---- Phase B staging + compute k=0..3 share one scheduler region ----
    stage_slot(2); stage_slot(3); stage_slot(4);
    stage_slot(5); stage_slot(6); stage_slot(7);
    su_p[wv][lane] = su_acc;

    compute_step(0); compute_step(1); compute_step(2); compute_step(3);
    __syncthreads();                      // barrier 2

#pragma unroll
    for (int k = 4; k < 16; ++k) compute_step(k);

    // ---- Epilogue: out[c,q] = acc + s_u[q] (sum the 8 wave partials) ----
    float* __restrict__ outb = out + ((size_t)(b * Cn + c0 + wv * 16)) * Qn;
#pragma unroll
    for (int n = 0; n < 4; ++n) {
        const int q = n * 16 + ql;
        float s = 0.f;
#pragma unroll
        for (int pw = 0; pw < 8; ++pw) s += su_p[pw][q];
#pragma unroll
        for (int rr = 0; rr < 4; ++rr)
            outb[(size_t)(hh * 4 + rr) * Qn + q] = acc[n][rr] + s;
    }
}

extern "C" void kernel_launch(void* const* d_in, const int* in_sizes, int n_in,
                              void* d_out, int out_size, void* d_ws, size_t ws_size,
                              hipStream_t stream) {
    const float* H = (const float*)d_in[0];
    const float* U = (const float*)d_in[1];
    const float* w = (const float*)d_in[2];
    float* out = (float*)d_out;
    sim_kernel<<<dim3(256), dim3(512), 0, stream>>>(H, U, w, out);
}

// Round 9
// 20.483 us; speedup vs baseline: 1.0099x; 1.0099x over previous
//
#include <hip/hip_runtime.h>
#include <hip/hip_bf16.h>

// B=64, C=512, Q=64, D=512, fp32 in/out.
// out[b,c,q] = sum_d H[b,c,d]*U'[b,q,d] + s_u[b,q]
//   U'[q,d] = w_hu[d]*U[q,d] + w_h[d]   (folds s_h into the GEMM)
//   s_u[q]  = sum_d w_u[d]*U[q,d]
// 256 blocks (1/CU) x 512 threads. R7 structure (split staging, scalar w
// loads, ring-4 H prefetch) with SOFT barriers: s_waitcnt lgkmcnt(0) +
// s_barrier only (no vmcnt drain) -- H register-prefetches stay in flight
// across both barriers. Cross-wave data through LDS is fully ordered by
// the lgkmcnt drain; H loads are wave-private registers.

#define Bn 64
#define Cn 512
#define Qn 64
#define Dn 512

typedef __bf16 bf16x8 __attribute__((ext_vector_type(8)));
typedef float  f32x4  __attribute__((ext_vector_type(4)));

__device__ __forceinline__ void soft_barrier() {
    __builtin_amdgcn_sched_barrier(0);
    asm volatile("s_waitcnt lgkmcnt(0)" ::: "memory");
    __builtin_amdgcn_s_barrier();
    __builtin_amdgcn_sched_barrier(0);
}

__global__ __launch_bounds__(512, 1)
void sim_kernel(const float* __restrict__ H, const float* __restrict__ U,
                const float* __restrict__ w, float* __restrict__ out)
{
    // Us[kt][hh][p][j]: element d = kt*32 + hh*8 + j of q with (q^(kt&7))==p
    __shared__ __bf16 Us[16][4][64][8];   // 64 KB
    __shared__ float  su_p[8][64];        // per-wave s_u partials (2 KB)

    // XCD-contiguous mapping: XCD x (= bid&7) owns batches 8x..8x+7.
    const int r  = (int)blockIdx.x;       // 0..255
    const int x  = r & 7;
    const int i  = r >> 3;                // 0..31
    const int b  = x * 8 + (i >> 2);
    const int c0 = (i & 3) * 128;

    const int t    = (int)threadIdx.x;
    const int wv   = t >> 6;              // wave 0..7: rows c0+wv*16..+15
    const int lane = t & 63;
    const int ql   = lane & 15;
    const int hh   = lane >> 4;

    // ---- H ring prologue: issued FIRST (oldest in the VMEM FIFO) ----
    const float* __restrict__ hp =
        H + ((size_t)(b * Cn + c0 + wv * 16 + ql)) * Dn + hh * 8;
    f32x4 ha[4], hb[4];
#pragma unroll
    for (int p = 0; p < 3; ++p) {
        ha[p] = *(const f32x4*)(hp + 32 * p);
        hb[p] = *(const f32x4*)(hp + 32 * p + 4);
    }

    // ---- staging: slot s (0..4095) = (kt, hv, q=lane); thread t owns
    // slots t + 512*j, j=0..7. (kt,hv) wave-uniform -> scalar w loads. ----
    const float* __restrict__ Ubase = U + ((size_t)(b * Qn + lane)) * Dn;
    float su_acc = 0.f;

    auto stage_slot = [&](int j) {
        const int slot = t + 512 * j;
        const int kt = __builtin_amdgcn_readfirstlane(slot >> 8);
        const int hv = __builtin_amdgcn_readfirstlane((slot >> 6) & 3);
        const int d0 = kt * 32 + hv * 8;
        f32x4 u0  = *(const f32x4*)(Ubase + d0);
        f32x4 u1  = *(const f32x4*)(Ubase + d0 + 4);
        f32x4 wh0 = *(const f32x4*)(w + d0);
        f32x4 wh1 = *(const f32x4*)(w + d0 + 4);
        f32x4 wu0 = *(const f32x4*)(w + 512 + d0);
        f32x4 wu1 = *(const f32x4*)(w + 512 + d0 + 4);
        f32x4 wm0 = *(const f32x4*)(w + 1024 + d0);
        f32x4 wm1 = *(const f32x4*)(w + 1024 + d0 + 4);
        bf16x8 v;
#pragma unroll
        for (int e = 0; e < 4; ++e) {
            su_acc += wu0[e] * u0[e] + wu1[e] * u1[e];
            v[e]     = (__bf16)__builtin_fmaf(wm0[e], u0[e], wh0[e]);
            v[e + 4] = (__bf16)__builtin_fmaf(wm1[e], u1[e], wh1[e]);
        }
        *(bf16x8*)&Us[kt][hv][lane ^ (kt & 7)][0] = v;
    };

    // ---- compute step ----
    f32x4 acc[4] = {{0.f,0.f,0.f,0.f},{0.f,0.f,0.f,0.f},
                    {0.f,0.f,0.f,0.f},{0.f,0.f,0.f,0.f}};

    auto compute_step = [&](int k) {
        f32x4 ca = ha[k & 3], cb = hb[k & 3];
        if (k + 3 < 16) {
            ha[(k + 3) & 3] = *(const f32x4*)(hp + 32 * (k + 3));
            hb[(k + 3) & 3] = *(const f32x4*)(hp + 32 * (k + 3) + 4);
        }
        bf16x8 a;
#pragma unroll
        for (int e = 0; e < 4; ++e) {
            a[e]     = (__bf16)ca[e];
            a[e + 4] = (__bf16)cb[e];
        }
        const int pq = ql ^ (k & 7);
        bf16x8 f0 = *(const bf16x8*)&Us[k][hh][pq +  0][0];
        bf16x8 f1 = *(const bf16x8*)&Us[k][hh][pq + 16][0];
        bf16x8 f2 = *(const bf16x8*)&Us[k][hh][pq + 32][0];
        bf16x8 f3 = *(const bf16x8*)&Us[k][hh][pq + 48][0];
        acc[0] = __builtin_amdgcn_mfma_f32_16x16x32_bf16(a, f0, acc[0], 0, 0, 0);
        acc[1] = __builtin_amdgcn_mfma_f32_16x16x32_bf16(a, f1, acc[1], 0, 0, 0);
        acc[2] = __builtin_amdgcn_mfma_f32_16x16x32_bf16(a, f2, acc[2], 0, 0, 0);
        acc[3] = __builtin_amdgcn_mfma_f32_16x16x32_bf16(a, f3, acc[3], 0, 0, 0);
    };

    // ---- Phase A: stage K-tiles 0..3 only (1/4 of staging) ----
    stage_slot(0);
    stage_slot(1);
    soft_barrier();                       // barrier 1: LDS drain only

    // ---- Phase B staging + compute k=0..3 share one scheduler region ----
    stage_slot(2); stage_slot(3); stage_slot(4);
    stage_slot(5); stage_slot(6); stage_slot(7);
    su_p[wv][lane] = su_acc;

    compute_step(0); compute_step(1); compute_step(2); compute_step(3);
    soft_barrier();                       // barrier 2: LDS drain only

#pragma unroll
    for (int k = 4; k < 16; ++k) compute_step(k);

    // ---- Epilogue: out[c,q] = acc + s_u[q] (sum the 8 wave partials) ----
    float* __restrict__ outb = out + ((size_t)(b * Cn + c0 + wv * 16)) * Qn;
#pragma unroll
    for (int n = 0; n < 4; ++n) {
        const int q = n * 16 + ql;
        float s = 0.f;
#pragma unroll
        for (int pw = 0; pw < 8; ++pw) s += su_p[pw][q];
#pragma unroll
        for (int rr = 0; rr < 4; ++rr)
            outb[(size_t)(hh * 4 + rr) * Qn + q] = acc[n][rr] + s;
    }
}

extern "C" void kernel_launch(void* const* d_in, const int* in_sizes, int n_in,
                              void* d_out, int out_size, void* d_ws, size_t ws_size,
                              hipStream_t stream) {
    const float* H = (const float*)d_in[0];
    const float* U = (const float*)d_in[1];
    const float* w = (const float*)d_in[2];
    float* out = (float*)d_out;
    sim_kernel<<<dim3(256), dim3(512), 0, stream>>>(H, U, w, out);
}

// Round 10
// 19.978 us; speedup vs baseline: 1.0354x; 1.0253x over previous
//
#include <hip/hip_runtime.h>
#include <hip/hip_bf16.h>

// B=64, C=512, Q=64, D=512, fp32 in/out.
// out[b,c,q] = sum_d H[b,c,d]*U'[b,q,d] + s_u[b,q]
//   U'[q,d] = w_hu[d]*U[q,d] + w_h[d]   (folds s_h into the GEMM)
//   s_u[q]  = sum_d w_u[d]*U[q,d]
// 256 blocks (1/CU) x 512 threads. Staging split: phase A stages K-tiles
// 0..3 (tiny bubble), barrier; phase B (K-tiles 4..15) shares a scheduler
// region with compute k=0..3 so it hides under MFMA+H-stream; barrier;
// compute k=4..15. Staging map is wave-uniform in (kt,hv) with
// readfirstlane-hoisted offsets -> all w reads are scalar s_loads and
// U[b] is read exactly once per block (16 vector loads/thread).
// [R7 configuration — best measured: 20.14 us]

#define Bn 64
#define Cn 512
#define Qn 64
#define Dn 512

typedef __bf16 bf16x8 __attribute__((ext_vector_type(8)));
typedef float  f32x4  __attribute__((ext_vector_type(4)));

__global__ __launch_bounds__(512, 1)
void sim_kernel(const float* __restrict__ H, const float* __restrict__ U,
                const float* __restrict__ w, float* __restrict__ out)
{
    // Us[kt][hh][p][j]: element d = kt*32 + hh*8 + j of q with (q^(kt&7))==p
    __shared__ __bf16 Us[16][4][64][8];   // 64 KB
    __shared__ float  su_p[8][64];        // per-wave s_u partials (2 KB)

    // XCD-contiguous mapping: XCD x (= bid&7) owns batches 8x..8x+7.
    const int r  = (int)blockIdx.x;       // 0..255
    const int x  = r & 7;
    const int i  = r >> 3;                // 0..31
    const int b  = x * 8 + (i >> 2);
    const int c0 = (i & 3) * 128;

    const int t    = (int)threadIdx.x;
    const int wv   = t >> 6;              // wave 0..7: rows c0+wv*16..+15
    const int lane = t & 63;
    const int ql   = lane & 15;
    const int hh   = lane >> 4;

    // ---- H ring prologue: issued FIRST ----
    const float* __restrict__ hp =
        H + ((size_t)(b * Cn + c0 + wv * 16 + ql)) * Dn + hh * 8;
    f32x4 ha[4], hb[4];
#pragma unroll
    for (int p = 0; p < 3; ++p) {
        ha[p] = *(const f32x4*)(hp + 32 * p);
        hb[p] = *(const f32x4*)(hp + 32 * p + 4);
    }

    // ---- staging: slot s (0..4095) = (kt, hv, q=lane); thread t owns
    // slots t + 512*j, j=0..7. (kt,hv) wave-uniform -> scalar w loads. ----
    const float* __restrict__ Ubase = U + ((size_t)(b * Qn + lane)) * Dn;
    float su_acc = 0.f;

    auto stage_slot = [&](int j) {
        const int slot = t + 512 * j;
        const int kt = __builtin_amdgcn_readfirstlane(slot >> 8);
        const int hv = __builtin_amdgcn_readfirstlane((slot >> 6) & 3);
        const int d0 = kt * 32 + hv * 8;
        f32x4 u0  = *(const f32x4*)(Ubase + d0);
        f32x4 u1  = *(const f32x4*)(Ubase + d0 + 4);
        f32x4 wh0 = *(const f32x4*)(w + d0);
        f32x4 wh1 = *(const f32x4*)(w + d0 + 4);
        f32x4 wu0 = *(const f32x4*)(w + 512 + d0);
        f32x4 wu1 = *(const f32x4*)(w + 512 + d0 + 4);
        f32x4 wm0 = *(const f32x4*)(w + 1024 + d0);
        f32x4 wm1 = *(const f32x4*)(w + 1024 + d0 + 4);
        bf16x8 v;
#pragma unroll
        for (int e = 0; e < 4; ++e) {
            su_acc += wu0[e] * u0[e] + wu1[e] * u1[e];
            v[e]     = (__bf16)__builtin_fmaf(wm0[e], u0[e], wh0[e]);
            v[e + 4] = (__bf16)__builtin_fmaf(wm1[e], u1[e], wh1[e]);
        }
        *(bf16x8*)&Us[kt][hv][lane ^ (kt & 7)][0] = v;
    };

    // ---- compute step ----
    f32x4 acc[4] = {{0.f,0.f,0.f,0.f},{0.f,0.f,0.f,0.f},
                    {0.f,0.f,0.f,0.f},{0.f,0.f,0.f,0.f}};

    auto compute_step = [&](int k) {
        f32x4 ca = ha[k & 3], cb = hb[k & 3];
        if (k + 3 < 16) {
            ha[(k + 3) & 3] = *(const f32x4*)(hp + 32 * (k + 3));
            hb[(k + 3) & 3] = *(const f32x4*)(hp + 32 * (k + 3) + 4);
        }
        bf16x8 a;
#pragma unroll
        for (int e = 0; e < 4; ++e) {
            a[e]     = (__bf16)ca[e];
            a[e + 4] = (__bf16)cb[e];
        }
        const int pq = ql ^ (k & 7);
        bf16x8 f0 = *(const bf16x8*)&Us[k][hh][pq +  0][0];
        bf16x8 f1 = *(const bf16x8*)&Us[k][hh][pq + 16][0];
        bf16x8 f2 = *(const bf16x8*)&Us[k][hh][pq + 32][0];
        bf16x8 f3 = *(const bf16x8*)&Us[k][hh][pq + 48][0];
        acc[0] = __builtin_amdgcn_mfma_f32_16x16x32_bf16(a, f0, acc[0], 0, 0, 0);
        acc[1] = __builtin_amdgcn_mfma_f32_16x16x32_bf16(a, f1, acc[1], 0, 0, 0);
        acc[2] = __builtin_amdgcn_mfma_f32_16x16x32_bf16(a, f2, acc[2], 0, 0, 0);
        acc[3] = __builtin_amdgcn_mfma_f32_16x16x32_bf16(a, f3, acc[3], 0, 0, 0);
    };

    // ---- Phase A: stage K-tiles 0..3 only (1/4 of staging) ----
    stage_slot(0);
    stage_slot(1);
    __syncthreads();                      // barrier 1 (small drain)

    // ---- Phase B staging + compute k=0..3 share one scheduler region ----
    stage_slot(2); stage_slot(3); stage_slot(4);
    stage_slot(5); stage_slot(6); stage_slot(7);
    su_p[wv][lane] = su_acc;

    compute_step(0); compute_step(1); compute_step(2); compute_step(3);
    __syncthreads();                      // barrier 2

#pragma unroll
    for (int k = 4; k < 16; ++k) compute_step(k);

    // ---- Epilogue: out[c,q] = acc + s_u[q] (sum the 8 wave partials) ----
    float* __restrict__ outb = out + ((size_t)(b * Cn + c0 + wv * 16)) * Qn;
#pragma unroll
    for (int n = 0; n < 4; ++n) {
        const int q = n * 16 + ql;
        float s = 0.f;
#pragma unroll
        for (int pw = 0; pw < 8; ++pw) s += su_p[pw][q];
#pragma unroll
        for (int rr = 0; rr < 4; ++rr)
            outb[(size_t)(hh * 4 + rr) * Qn + q] = acc[n][rr] + s;
    }
}

extern "C" void kernel_launch(void* const* d_in, const int* in_sizes, int n_in,
                              void* d_out, int out_size, void* d_ws, size_t ws_size,
                              hipStream_t stream) {
    const float* H = (const float*)d_in[0];
    const float* U = (const float*)d_in[1];
    const float* w = (const float*)d_in[2];
    float* out = (float*)d_out;
    sim_kernel<<<dim3(256), dim3(512), 0, stream>>>(H, U, w, out);
}